// Round 1
// baseline (173.978 us; speedup 1.0000x reference)
//
#include <hip/hip_runtime.h>
#include <math.h>

#define NN 18
#define T_STEPS 1280
#define T1LEN 1278   // T-2 (after conv1)
#define T2LEN 1276   // T-4 (after conv2)

// ---------------- K1: normalize (flat; reshape is a no-op) ----------------
__global__ void k_norm(const float* __restrict__ x, float* __restrict__ X, int n) {
    int i = blockIdx.x * 256 + threadIdx.x;
    if (i < n) {
        float v = x[i];
        X[i] = v / fmaxf(fabsf(v), 1e-12f);
    }
}

// ---------------- K0: transpose conv2 weights to [conv][k][ci][co] ----------------
__global__ void k_wprep(const float* __restrict__ wa, const float* __restrict__ wb,
                        const float* __restrict__ wc, float* __restrict__ wt) {
    int i = blockIdx.x * 256 + threadIdx.x;
    if (i >= 12288) return;
    int co = i & 63;
    int rest = i >> 6;       // k*64 + ci
    int ci = rest & 63;
    int k = rest >> 6;
    int src = co * 192 + ci * 3 + k;
    wt[i] = wa[src];
    wt[12288 + i] = wb[src];
    wt[24576 + i] = wc[src];
}

// ---------------- K2: conv1 (C_in=1) + GLU ----------------
__global__ __launch_bounds__(256) void k_conv1(const float* __restrict__ X,
        const float* __restrict__ w1a, const float* __restrict__ b1a,
        const float* __restrict__ w1b, const float* __restrict__ b1b,
        const float* __restrict__ w1c, const float* __restrict__ b1c,
        float* __restrict__ T0) {
    int gid = blockIdx.x * 256 + threadIdx.x;
    if (gid >= T1LEN * NN * 64) return;
    int c = gid & 63;
    int pos = gid >> 6;          // t'*18 + n
    int n = pos % NN;
    int tp = pos / NN;
    float pa = b1a[c], pb = b1b[c], pc_ = b1c[c];
    #pragma unroll
    for (int k = 0; k < 3; ++k) {
        float xv = X[(tp + k) * NN + n];
        pa  = fmaf(w1a[c * 3 + k], xv, pa);
        pb  = fmaf(w1b[c * 3 + k], xv, pb);
        pc_ = fmaf(w1c[c * 3 + k], xv, pc_);
    }
    float q = 1.0f / (1.0f + expf(-pb));
    float h = pa * q + pc_;
    T0[gid] = fmaxf(h, 0.0f);
}

// ---------------- K3: Cheb K=1 linear (64x64) + relu ----------------
__global__ __launch_bounds__(256) void k_cheb(const float* __restrict__ T0,
        const float* __restrict__ cw, const float* __restrict__ cb,
        float* __restrict__ T1) {
    __shared__ float tile[64][65];
    int p0 = blockIdx.x * 64;
    int np = min(64, T1LEN * NN - p0);
    for (int idx = threadIdx.x; idx < np * 64; idx += 256) {
        int r = idx >> 6, c = idx & 63;
        tile[r][c] = T0[(p0 + r) * 64 + c];
    }
    __syncthreads();
    int d = threadIdx.x & 63;
    int w = threadIdx.x >> 6;     // 0..3, 16 positions each
    float acc[16];
    float bias = cb[d];
    #pragma unroll
    for (int j = 0; j < 16; ++j) acc[j] = bias;
    for (int cc = 0; cc < 64; ++cc) {
        float wv = cw[cc * 64 + d];
        #pragma unroll
        for (int j = 0; j < 16; ++j)
            acc[j] = fmaf(tile[w * 16 + j][cc], wv, acc[j]);
    }
    #pragma unroll
    for (int j = 0; j < 16; ++j) {
        int p = w * 16 + j;
        if (p < np) T1[(p0 + p) * 64 + d] = fmaxf(acc[j], 0.0f);
    }
}

// ---------------- K4: conv2 (64->64, k=3) + GLU ----------------
__global__ __launch_bounds__(256) void k_conv2(const float* __restrict__ T1,
        const float* __restrict__ wt,   // [3 conv][3 k][64 ci][64 co]
        const float* __restrict__ b2a, const float* __restrict__ b2b,
        const float* __restrict__ b2c,
        float* __restrict__ T2) {
    __shared__ float tin[66][65];   // [t_local][c], pad 65 -> conflict-free staging
    int t0 = blockIdx.x * 64;
    int n  = blockIdx.y;
    int nt = min(64, T2LEN - t0);
    int nrows = nt + 2;
    for (int idx = threadIdx.x; idx < nrows * 64; idx += 256) {
        int r = idx >> 6, c = idx & 63;
        tin[r][c] = T1[((t0 + r) * NN + n) * 64 + c];
    }
    __syncthreads();
    int co = threadIdx.x & 63;
    int w  = threadIdx.x >> 6;      // wave id, 16 t each
    int tw = w * 16;
    float accA[16], accB[16], accC[16];
    float ba = b2a[co], bb = b2b[co], bc = b2c[co];
    #pragma unroll
    for (int j = 0; j < 16; ++j) { accA[j] = ba; accB[j] = bb; accC[j] = bc; }
    for (int ci = 0; ci < 64; ++ci) {
        float in[18];
        #pragma unroll
        for (int j = 0; j < 18; ++j) in[j] = tin[tw + j][ci];   // wave-broadcast reads
        #pragma unroll
        for (int k = 0; k < 3; ++k) {
            float wva = wt[(k * 64 + ci) * 64 + co];
            float wvb = wt[12288 + (k * 64 + ci) * 64 + co];
            float wvc = wt[24576 + (k * 64 + ci) * 64 + co];
            #pragma unroll
            for (int j = 0; j < 16; ++j) {
                accA[j] = fmaf(wva, in[j + k], accA[j]);
                accB[j] = fmaf(wvb, in[j + k], accB[j]);
                accC[j] = fmaf(wvc, in[j + k], accC[j]);
            }
        }
    }
    #pragma unroll
    for (int j = 0; j < 16; ++j) {
        int t = tw + j;
        if (t < nt) {
            float q = 1.0f / (1.0f + expf(-accB[j]));
            float h = accA[j] * q + accC[j];
            T2[((t0 + t) * NN + n) * 64 + co] = fmaxf(h, 0.0f);
        }
    }
}

// ---------------- K5: per-node BN stats (training mode, biased var) ----------------
__global__ __launch_bounds__(256) void k_stats(const float* __restrict__ T2,
                                               float* __restrict__ stats) {
    int n = blockIdx.x;
    float s = 0.f, sq = 0.f;
    for (int i = threadIdx.x; i < T2LEN * 64; i += 256) {
        int t = i >> 6, c = i & 63;
        float v = T2[(t * NN + n) * 64 + c];
        s += v;
        sq = fmaf(v, v, sq);
    }
    __shared__ float rs[256], rq[256];
    rs[threadIdx.x] = s; rq[threadIdx.x] = sq;
    __syncthreads();
    for (int off = 128; off > 0; off >>= 1) {
        if (threadIdx.x < off) {
            rs[threadIdx.x] += rs[threadIdx.x + off];
            rq[threadIdx.x] += rq[threadIdx.x + off];
        }
        __syncthreads();
    }
    if (threadIdx.x == 0) {
        float cnt = (float)(T2LEN * 64);
        float mean = rs[0] / cnt;
        float var = rq[0] / cnt - mean * mean;
        stats[n * 2]     = mean;
        stats[n * 2 + 1] = rsqrtf(var + 1e-5f);
    }
}

// ---------------- K6: BN apply + relu + dot with fc_w (partials) ----------------
#define DOT_BLOCKS 512
__global__ __launch_bounds__(256) void k_dot(const float* __restrict__ T2,
        const float* __restrict__ stats,
        const float* __restrict__ gamma, const float* __restrict__ beta,
        const float* __restrict__ fcw, float* __restrict__ partials) {
    float acc = 0.f;
    const int total = T2LEN * NN * 64;
    for (int i = blockIdx.x * 256 + threadIdx.x; i < total; i += DOT_BLOCKS * 256) {
        int n = (i >> 6) % NN;
        float v = (T2[i] - stats[n * 2]) * stats[n * 2 + 1] * gamma[n] + beta[n];
        v = fmaxf(v, 0.f);
        acc = fmaf(v, fcw[i], acc);
    }
    __shared__ float r[256];
    r[threadIdx.x] = acc;
    __syncthreads();
    for (int off = 128; off > 0; off >>= 1) {
        if (threadIdx.x < off) r[threadIdx.x] += r[threadIdx.x + off];
        __syncthreads();
    }
    if (threadIdx.x == 0) partials[blockIdx.x] = r[0];
}

// ---------------- K7: final reduce + fc_b ----------------
__global__ __launch_bounds__(512) void k_final(const float* __restrict__ partials,
                                               const float* __restrict__ fcb,
                                               float* __restrict__ out) {
    __shared__ float r[512];
    r[threadIdx.x] = partials[threadIdx.x];
    __syncthreads();
    for (int off = 256; off > 0; off >>= 1) {
        if (threadIdx.x < off) r[threadIdx.x] += r[threadIdx.x + off];
        __syncthreads();
    }
    if (threadIdx.x == 0) out[0] = r[0] + fcb[0];
}

extern "C" void kernel_launch(void* const* d_in, const int* in_sizes, int n_in,
                              void* d_out, int out_size, void* d_ws, size_t ws_size,
                              hipStream_t stream) {
    const float* x     = (const float*)d_in[0];
    // d_in[1] edge_index, d_in[2] edge_weight: unused (ChebConv K=1 -> identity term only)
    const float* w1a   = (const float*)d_in[3];
    const float* b1a   = (const float*)d_in[4];
    const float* w1b   = (const float*)d_in[5];
    const float* b1b   = (const float*)d_in[6];
    const float* w1c   = (const float*)d_in[7];
    const float* b1c   = (const float*)d_in[8];
    const float* chw   = (const float*)d_in[9];
    const float* chb   = (const float*)d_in[10];
    const float* w2a   = (const float*)d_in[11];
    const float* b2a   = (const float*)d_in[12];
    const float* w2b   = (const float*)d_in[13];
    const float* b2b   = (const float*)d_in[14];
    const float* w2c   = (const float*)d_in[15];
    const float* b2c   = (const float*)d_in[16];
    const float* gamma = (const float*)d_in[17];
    const float* beta  = (const float*)d_in[18];
    const float* fcw   = (const float*)d_in[19];
    const float* fcb   = (const float*)d_in[20];
    float* out = (float*)d_out;

    float* ws = (float*)d_ws;
    float* X    = ws;                 // 23040
    float* T0   = X  + 23040;         // 1472256
    float* T1v  = T0 + 1472256;       // 1472256
    float* T2v  = T1v + 1472256;      // 1469952
    float* WT   = T2v + 1469952;      // 36864
    float* stats = WT + 36864;        // 36 (use 64)
    float* partials = stats + 64;     // 512

    k_norm<<<(23040 + 255) / 256, 256, 0, stream>>>(x, X, 23040);
    k_wprep<<<48, 256, 0, stream>>>(w2a, w2b, w2c, WT);
    k_conv1<<<(T1LEN * NN * 64 + 255) / 256, 256, 0, stream>>>(
        X, w1a, b1a, w1b, b1b, w1c, b1c, T0);
    k_cheb<<<(T1LEN * NN + 63) / 64, 256, 0, stream>>>(T0, chw, chb, T1v);
    k_conv2<<<dim3((T2LEN + 63) / 64, NN), 256, 0, stream>>>(
        T1v, WT, b2a, b2b, b2c, T2v);
    k_stats<<<NN, 256, 0, stream>>>(T2v, stats);
    k_dot<<<DOT_BLOCKS, 256, 0, stream>>>(T2v, stats, gamma, beta, fcw, partials);
    k_final<<<1, 512, 0, stream>>>(partials, fcb, out);
}

// Round 2
// 76.140 us; speedup vs baseline: 2.2850x; 2.2850x over previous
//
#include <hip/hip_runtime.h>
#include <math.h>

#define NN 18
#define T_STEPS 1280
#define T1LEN 1278   // T-2 (after conv1)
#define T2LEN 1276   // T-4 (after conv2)
#define NPOS1 (T1LEN * NN)   // 23004
#define XTOT  (T_STEPS * NN) // 23040
#define NCHUNK2 ((T2LEN + 63) / 64)  // 20

// ---------------- K0: transpose conv2 weights to [conv][k][ci][co] ----------------
__global__ void k_wprep(const float* __restrict__ wa, const float* __restrict__ wb,
                        const float* __restrict__ wc, float* __restrict__ wt) {
    int i = blockIdx.x * 256 + threadIdx.x;
    if (i >= 12288) return;
    int co = i & 63;
    int rest = i >> 6;       // k*64 + ci
    int ci = rest & 63;
    int k = rest >> 6;
    int src = co * 192 + ci * 3 + k;
    wt[i] = wa[src];
    wt[12288 + i] = wb[src];
    wt[24576 + i] = wc[src];
}

// ---------------- K1: fused normalize + conv1(GLU) + cheb(64x64)+relu ----------------
__global__ __launch_bounds__(256) void k_fused1(const float* __restrict__ x,
        const float* __restrict__ w1a, const float* __restrict__ b1a,
        const float* __restrict__ w1b, const float* __restrict__ b1b,
        const float* __restrict__ w1c, const float* __restrict__ b1c,
        const float* __restrict__ cw, const float* __restrict__ cb,
        float* __restrict__ T1) {
    __shared__ float xs[104];
    __shared__ float tile[64][65];
    int p0 = blockIdx.x * 64;
    int np = min(64, NPOS1 - p0);
    // stage + normalize 100 x values (positions p0..p0+63 need x[p..p+36])
    for (int idx = threadIdx.x; idx < 100; idx += 256) {
        int g = p0 + idx;
        float v = (g < XTOT) ? x[g] : 0.f;
        xs[idx] = v / fmaxf(fabsf(v), 1e-12f);
    }
    __syncthreads();
    int c = threadIdx.x & 63;
    int w = threadIdx.x >> 6;     // 0..3, 16 positions each
    // conv1 for channel c, 16 positions
    float wa0 = w1a[c*3], wa1 = w1a[c*3+1], wa2 = w1a[c*3+2];
    float wb0 = w1b[c*3], wb1 = w1b[c*3+1], wb2 = w1b[c*3+2];
    float wc0 = w1c[c*3], wc1 = w1c[c*3+1], wc2 = w1c[c*3+2];
    float ba = b1a[c], bb = b1b[c], bc = b1c[c];
    #pragma unroll
    for (int j = 0; j < 16; ++j) {
        int pl = w * 16 + j;
        float x0 = xs[pl], x1 = xs[pl + 18], x2 = xs[pl + 36];
        float pa = fmaf(wa2, x2, fmaf(wa1, x1, fmaf(wa0, x0, ba)));
        float pb = fmaf(wb2, x2, fmaf(wb1, x1, fmaf(wb0, x0, bb)));
        float pc_ = fmaf(wc2, x2, fmaf(wc1, x1, fmaf(wc0, x0, bc)));
        float q = 1.0f / (1.0f + expf(-pb));
        tile[pl][c] = fmaxf(pa * q + pc_, 0.f);
    }
    __syncthreads();
    // cheb: d = c (output channel), same 16 positions
    float acc[16];
    float bias = cb[c];
    #pragma unroll
    for (int j = 0; j < 16; ++j) acc[j] = bias;
    for (int cc = 0; cc < 64; ++cc) {
        float wv = cw[cc * 64 + c];
        #pragma unroll
        for (int j = 0; j < 16; ++j)
            acc[j] = fmaf(tile[w * 16 + j][cc], wv, acc[j]);
    }
    #pragma unroll
    for (int j = 0; j < 16; ++j) {
        int p = w * 16 + j;
        if (p < np) T1[(p0 + p) * 64 + c] = fmaxf(acc[j], 0.0f);
    }
}

// ---------------- K2: conv2 (64->64, k=3) + GLU + per-block BN partials ----------------
__global__ __launch_bounds__(256) void k_conv2(const float* __restrict__ T1,
        const float* __restrict__ wt,   // [3 conv][3 k][64 ci][64 co]
        const float* __restrict__ b2a, const float* __restrict__ b2b,
        const float* __restrict__ b2c,
        float* __restrict__ T2, float* __restrict__ partials) {
    __shared__ float tin[66][65];   // [t_local][c]
    int t0 = blockIdx.x * 64;
    int n  = blockIdx.y;
    int nt = min(64, T2LEN - t0);
    int nrows = nt + 2;
    for (int idx = threadIdx.x; idx < nrows * 64; idx += 256) {
        int r = idx >> 6, c = idx & 63;
        tin[r][c] = T1[((t0 + r) * NN + n) * 64 + c];
    }
    __syncthreads();
    int co = threadIdx.x & 63;
    int w  = threadIdx.x >> 6;
    int tw = w * 16;
    float accA[16], accB[16], accC[16];
    float ba = b2a[co], bb = b2b[co], bc = b2c[co];
    #pragma unroll
    for (int j = 0; j < 16; ++j) { accA[j] = ba; accB[j] = bb; accC[j] = bc; }
    for (int ci = 0; ci < 64; ++ci) {
        float in[18];
        #pragma unroll
        for (int j = 0; j < 18; ++j) in[j] = tin[tw + j][ci];
        #pragma unroll
        for (int k = 0; k < 3; ++k) {
            float wva = wt[(k * 64 + ci) * 64 + co];
            float wvb = wt[12288 + (k * 64 + ci) * 64 + co];
            float wvc = wt[24576 + (k * 64 + ci) * 64 + co];
            #pragma unroll
            for (int j = 0; j < 16; ++j) {
                accA[j] = fmaf(wva, in[j + k], accA[j]);
                accB[j] = fmaf(wvb, in[j + k], accB[j]);
                accC[j] = fmaf(wvc, in[j + k], accC[j]);
            }
        }
    }
    float s = 0.f, sq = 0.f;
    #pragma unroll
    for (int j = 0; j < 16; ++j) {
        int t = tw + j;
        if (t < nt) {
            float q = 1.0f / (1.0f + expf(-accB[j]));
            float h = fmaxf(accA[j] * q + accC[j], 0.0f);
            T2[((t0 + t) * NN + n) * 64 + co] = h;
            s += h;
            sq = fmaf(h, h, sq);
        }
    }
    __syncthreads();  // done with tin
    __shared__ float rs[256], rq[256];
    rs[threadIdx.x] = s; rq[threadIdx.x] = sq;
    __syncthreads();
    for (int off = 128; off > 0; off >>= 1) {
        if (threadIdx.x < off) {
            rs[threadIdx.x] += rs[threadIdx.x + off];
            rq[threadIdx.x] += rq[threadIdx.x + off];
        }
        __syncthreads();
    }
    if (threadIdx.x == 0) {
        partials[(n * NCHUNK2 + blockIdx.x) * 2]     = rs[0];
        partials[(n * NCHUNK2 + blockIdx.x) * 2 + 1] = rq[0];
    }
}

// ---------------- K3: finalize BN stats per node ----------------
__global__ __launch_bounds__(64) void k_statsfin(const float* __restrict__ partials,
                                                 float* __restrict__ stats) {
    int n = blockIdx.x;
    int l = threadIdx.x;
    float s = (l < NCHUNK2) ? partials[(n * NCHUNK2 + l) * 2]     : 0.f;
    float q = (l < NCHUNK2) ? partials[(n * NCHUNK2 + l) * 2 + 1] : 0.f;
    #pragma unroll
    for (int off = 32; off > 0; off >>= 1) {
        s += __shfl_down(s, off);
        q += __shfl_down(q, off);
    }
    if (l == 0) {
        float cnt = (float)(T2LEN * 64);
        float mean = s / cnt;
        float var = q / cnt - mean * mean;
        stats[n * 2]     = mean;
        stats[n * 2 + 1] = rsqrtf(var + 1e-5f);
    }
}

// ---------------- K4: BN apply + relu + dot with fc_w (partials) ----------------
#define DOT_BLOCKS 512
__global__ __launch_bounds__(256) void k_dot(const float* __restrict__ T2,
        const float* __restrict__ stats,
        const float* __restrict__ gamma, const float* __restrict__ beta,
        const float* __restrict__ fcw, float* __restrict__ dpart) {
    float acc = 0.f;
    const int total = T2LEN * NN * 64;
    for (int i = blockIdx.x * 256 + threadIdx.x; i < total; i += DOT_BLOCKS * 256) {
        int n = (i >> 6) % NN;
        float v = (T2[i] - stats[n * 2]) * stats[n * 2 + 1] * gamma[n] + beta[n];
        v = fmaxf(v, 0.f);
        acc = fmaf(v, fcw[i], acc);
    }
    __shared__ float r[256];
    r[threadIdx.x] = acc;
    __syncthreads();
    for (int off = 128; off > 0; off >>= 1) {
        if (threadIdx.x < off) r[threadIdx.x] += r[threadIdx.x + off];
        __syncthreads();
    }
    if (threadIdx.x == 0) dpart[blockIdx.x] = r[0];
}

// ---------------- K5: final reduce + fc_b ----------------
__global__ __launch_bounds__(512) void k_final(const float* __restrict__ dpart,
                                               const float* __restrict__ fcb,
                                               float* __restrict__ out) {
    __shared__ float r[512];
    r[threadIdx.x] = dpart[threadIdx.x];
    __syncthreads();
    for (int off = 256; off > 0; off >>= 1) {
        if (threadIdx.x < off) r[threadIdx.x] += r[threadIdx.x + off];
        __syncthreads();
    }
    if (threadIdx.x == 0) out[0] = r[0] + fcb[0];
}

extern "C" void kernel_launch(void* const* d_in, const int* in_sizes, int n_in,
                              void* d_out, int out_size, void* d_ws, size_t ws_size,
                              hipStream_t stream) {
    const float* x     = (const float*)d_in[0];
    // d_in[1] edge_index, d_in[2] edge_weight: unused (ChebConv K=1 -> identity only)
    const float* w1a   = (const float*)d_in[3];
    const float* b1a   = (const float*)d_in[4];
    const float* w1b   = (const float*)d_in[5];
    const float* b1b   = (const float*)d_in[6];
    const float* w1c   = (const float*)d_in[7];
    const float* b1c   = (const float*)d_in[8];
    const float* chw   = (const float*)d_in[9];
    const float* chb   = (const float*)d_in[10];
    const float* w2a   = (const float*)d_in[11];
    const float* b2a   = (const float*)d_in[12];
    const float* w2b   = (const float*)d_in[13];
    const float* b2b   = (const float*)d_in[14];
    const float* w2c   = (const float*)d_in[15];
    const float* b2c   = (const float*)d_in[16];
    const float* gamma = (const float*)d_in[17];
    const float* beta  = (const float*)d_in[18];
    const float* fcw   = (const float*)d_in[19];
    const float* fcb   = (const float*)d_in[20];
    float* out = (float*)d_out;

    float* ws = (float*)d_ws;
    float* T1v   = ws;                  // 1472256
    float* T2v   = T1v + 1472256;       // 1469952
    float* WT    = T2v + 1469952;       // 36864
    float* parts = WT + 36864;          // 18*20*2 = 720
    float* stats = parts + 768;         // 36 (use 64)
    float* dpart = stats + 64;          // 512

    k_wprep<<<48, 256, 0, stream>>>(w2a, w2b, w2c, WT);
    k_fused1<<<(NPOS1 + 63) / 64, 256, 0, stream>>>(
        x, w1a, b1a, w1b, b1b, w1c, b1c, chw, chb, T1v);
    k_conv2<<<dim3(NCHUNK2, NN), 256, 0, stream>>>(
        T1v, WT, b2a, b2b, b2c, T2v, parts);
    k_statsfin<<<NN, 64, 0, stream>>>(parts, stats);
    k_dot<<<DOT_BLOCKS, 256, 0, stream>>>(T2v, stats, gamma, beta, fcw, dpart);
    k_final<<<1, 512, 0, stream>>>(dpart, fcb, out);
}

// Round 3
// 65.969 us; speedup vs baseline: 2.6373x; 1.1542x over previous
//
#include <hip/hip_runtime.h>
#include <math.h>

#define NN 18
#define T_STEPS 1280
#define T1LEN 1278   // T-2 (after conv1)
#define T2LEN 1276   // T-4 (after conv2)
#define NPOS1 (T1LEN * NN)   // 23004
#define XTOT  (T_STEPS * NN) // 23040
#define TC2 32
#define NCHUNK2 ((T2LEN + TC2 - 1) / TC2)  // 40
#define PC1 32
#define NCHUNK1 ((NPOS1 + PC1 - 1) / PC1)  // 719

// ---------------- K0: transpose conv2 weights to [conv*3+k][ci][co] ----------------
__global__ void k_wprep(const float* __restrict__ wa, const float* __restrict__ wb,
                        const float* __restrict__ wc, float* __restrict__ wt) {
    int i = blockIdx.x * 256 + threadIdx.x;
    if (i >= 12288) return;
    int co = i & 63;
    int rest = i >> 6;       // k*64 + ci
    int ci = rest & 63;
    int k = rest >> 6;
    int src = co * 192 + ci * 3 + k;
    wt[i] = wa[src];           // conv a: m = 0*3+k
    wt[12288 + i] = wb[src];   // conv b: m = 1*3+k
    wt[24576 + i] = wc[src];   // conv c: m = 2*3+k
}

// ---------------- K1: fused normalize + conv1(GLU) + cheb(64x64)+relu ----------------
__global__ __launch_bounds__(256) void k_fused1(const float* __restrict__ x,
        const float* __restrict__ w1a, const float* __restrict__ b1a,
        const float* __restrict__ w1b, const float* __restrict__ b1b,
        const float* __restrict__ w1c, const float* __restrict__ b1c,
        const float* __restrict__ cw, const float* __restrict__ cb,
        float* __restrict__ T1) {
    __shared__ float xs[72];        // 32 positions + 36 halo
    __shared__ float tile[PC1][65];
    int p0 = blockIdx.x * PC1;
    int np = min(PC1, NPOS1 - p0);
    for (int idx = threadIdx.x; idx < PC1 + 36; idx += 256) {
        int g = p0 + idx;
        float v = (g < XTOT) ? x[g] : 0.f;
        xs[idx] = v / fmaxf(fabsf(v), 1e-12f);
    }
    __syncthreads();
    int c = threadIdx.x & 63;
    int w = threadIdx.x >> 6;     // 0..3, 8 positions each
    float wa0 = w1a[c*3], wa1 = w1a[c*3+1], wa2 = w1a[c*3+2];
    float wb0 = w1b[c*3], wb1 = w1b[c*3+1], wb2 = w1b[c*3+2];
    float wc0 = w1c[c*3], wc1 = w1c[c*3+1], wc2 = w1c[c*3+2];
    float ba = b1a[c], bb = b1b[c], bc = b1c[c];
    #pragma unroll
    for (int j = 0; j < 8; ++j) {
        int pl = w * 8 + j;
        float x0 = xs[pl], x1 = xs[pl + 18], x2 = xs[pl + 36];
        float pa = fmaf(wa2, x2, fmaf(wa1, x1, fmaf(wa0, x0, ba)));
        float pb = fmaf(wb2, x2, fmaf(wb1, x1, fmaf(wb0, x0, bb)));
        float pc_ = fmaf(wc2, x2, fmaf(wc1, x1, fmaf(wc0, x0, bc)));
        float q = 1.0f / (1.0f + expf(-pb));
        tile[pl][c] = fmaxf(pa * q + pc_, 0.f);
    }
    __syncthreads();
    float acc[8];
    float bias = cb[c];
    #pragma unroll
    for (int j = 0; j < 8; ++j) acc[j] = bias;
    float wcur = cw[c];           // cc = 0
    for (int cc = 0; cc < 64; ++cc) {
        float wnxt = cw[((cc + 1) & 63) * 64 + c];
        #pragma unroll
        for (int j = 0; j < 8; ++j)
            acc[j] = fmaf(tile[w * 8 + j][cc], wcur, acc[j]);
        wcur = wnxt;
    }
    #pragma unroll
    for (int j = 0; j < 8; ++j) {
        int p = w * 8 + j;
        if (p < np) T1[(p0 + p) * 64 + c] = fmaxf(acc[j], 0.0f);
    }
}

// ---------------- K2: conv2 (64->64, k=3) + GLU + per-block BN partials ----------------
__global__ __launch_bounds__(256) void k_conv2(const float* __restrict__ T1,
        const float* __restrict__ wt,   // [m=conv*3+k][64 ci][64 co]
        const float* __restrict__ b2a, const float* __restrict__ b2b,
        const float* __restrict__ b2c,
        float* __restrict__ T2, float* __restrict__ partials) {
    __shared__ float tin[TC2 + 2][65];
    int t0 = blockIdx.x * TC2;
    int n  = blockIdx.y;
    int nt = min(TC2, T2LEN - t0);
    int nrows = min(TC2 + 2, T1LEN - t0);
    for (int idx = threadIdx.x; idx < nrows * 64; idx += 256) {
        int r = idx >> 6, c = idx & 63;
        tin[r][c] = T1[((t0 + r) * NN + n) * 64 + c];
    }
    __syncthreads();
    int co = threadIdx.x & 63;
    int w  = threadIdx.x >> 6;
    int tw = w * 8;               // 8 t per wave
    float accA[8], accB[8], accC[8];
    float ba = b2a[co], bb = b2b[co], bc = b2c[co];
    #pragma unroll
    for (int j = 0; j < 8; ++j) { accA[j] = ba; accB[j] = bb; accC[j] = bc; }
    float wcur[9], wnxt[9];
    #pragma unroll
    for (int m = 0; m < 9; ++m) wcur[m] = wt[m * 4096 + co];  // ci = 0
    for (int ci = 0; ci < 64; ++ci) {
        const float* wn = wt + ((ci + 1) & 63) * 64 + co;
        #pragma unroll
        for (int m = 0; m < 9; ++m) wnxt[m] = wn[m * 4096];
        float in[10];
        #pragma unroll
        for (int j = 0; j < 10; ++j) in[j] = tin[tw + j][ci];
        #pragma unroll
        for (int k = 0; k < 3; ++k) {
            #pragma unroll
            for (int j = 0; j < 8; ++j) {
                accA[j] = fmaf(wcur[k],     in[j + k], accA[j]);
                accB[j] = fmaf(wcur[3 + k], in[j + k], accB[j]);
                accC[j] = fmaf(wcur[6 + k], in[j + k], accC[j]);
            }
        }
        #pragma unroll
        for (int m = 0; m < 9; ++m) wcur[m] = wnxt[m];
    }
    float s = 0.f, sq = 0.f;
    #pragma unroll
    for (int j = 0; j < 8; ++j) {
        int t = tw + j;
        if (t < nt) {
            float q = 1.0f / (1.0f + expf(-accB[j]));
            float h = fmaxf(accA[j] * q + accC[j], 0.0f);
            T2[((t0 + t) * NN + n) * 64 + co] = h;
            s += h;
            sq = fmaf(h, h, sq);
        }
    }
    __syncthreads();
    __shared__ float rs[256], rq[256];
    rs[threadIdx.x] = s; rq[threadIdx.x] = sq;
    __syncthreads();
    for (int off = 128; off > 0; off >>= 1) {
        if (threadIdx.x < off) {
            rs[threadIdx.x] += rs[threadIdx.x + off];
            rq[threadIdx.x] += rq[threadIdx.x + off];
        }
        __syncthreads();
    }
    if (threadIdx.x == 0) {
        partials[(n * NCHUNK2 + blockIdx.x) * 2]     = rs[0];
        partials[(n * NCHUNK2 + blockIdx.x) * 2 + 1] = rq[0];
    }
}

// ---------------- K3: finalize BN stats per node ----------------
__global__ __launch_bounds__(64) void k_statsfin(const float* __restrict__ partials,
                                                 float* __restrict__ stats) {
    int n = blockIdx.x;
    int l = threadIdx.x;
    float s = (l < NCHUNK2) ? partials[(n * NCHUNK2 + l) * 2]     : 0.f;
    float q = (l < NCHUNK2) ? partials[(n * NCHUNK2 + l) * 2 + 1] : 0.f;
    #pragma unroll
    for (int off = 32; off > 0; off >>= 1) {
        s += __shfl_down(s, off);
        q += __shfl_down(q, off);
    }
    if (l == 0) {
        float cnt = (float)(T2LEN * 64);
        float mean = s / cnt;
        float var = q / cnt - mean * mean;
        stats[n * 2]     = mean;
        stats[n * 2 + 1] = rsqrtf(var + 1e-5f);
    }
}

// ---------------- K4: BN apply + relu + dot with fc_w (float4) ----------------
#define DOT_BLOCKS 512
__global__ __launch_bounds__(256) void k_dot(const float* __restrict__ T2,
        const float* __restrict__ stats,
        const float* __restrict__ gamma, const float* __restrict__ beta,
        const float* __restrict__ fcw, float* __restrict__ dpart) {
    float acc = 0.f;
    const int total4 = T2LEN * NN * 64 / 4;
    const float4* T24 = (const float4*)T2;
    const float4* fw4 = (const float4*)fcw;
    for (int i = blockIdx.x * 256 + threadIdx.x; i < total4; i += DOT_BLOCKS * 256) {
        float4 t = T24[i];
        float4 f = fw4[i];
        int n = (i >> 4) % NN;            // (4i >> 6) % NN
        float mu = stats[n * 2], is = stats[n * 2 + 1];
        float g = gamma[n], bt = beta[n];
        float v0 = fmaxf((t.x - mu) * is * g + bt, 0.f);
        float v1 = fmaxf((t.y - mu) * is * g + bt, 0.f);
        float v2 = fmaxf((t.z - mu) * is * g + bt, 0.f);
        float v3 = fmaxf((t.w - mu) * is * g + bt, 0.f);
        acc = fmaf(v0, f.x, acc);
        acc = fmaf(v1, f.y, acc);
        acc = fmaf(v2, f.z, acc);
        acc = fmaf(v3, f.w, acc);
    }
    __shared__ float r[256];
    r[threadIdx.x] = acc;
    __syncthreads();
    for (int off = 128; off > 0; off >>= 1) {
        if (threadIdx.x < off) r[threadIdx.x] += r[threadIdx.x + off];
        __syncthreads();
    }
    if (threadIdx.x == 0) dpart[blockIdx.x] = r[0];
}

// ---------------- K5: final reduce + fc_b ----------------
__global__ __launch_bounds__(512) void k_final(const float* __restrict__ dpart,
                                               const float* __restrict__ fcb,
                                               float* __restrict__ out) {
    __shared__ float r[512];
    r[threadIdx.x] = dpart[threadIdx.x];
    __syncthreads();
    for (int off = 256; off > 0; off >>= 1) {
        if (threadIdx.x < off) r[threadIdx.x] += r[threadIdx.x + off];
        __syncthreads();
    }
    if (threadIdx.x == 0) out[0] = r[0] + fcb[0];
}

extern "C" void kernel_launch(void* const* d_in, const int* in_sizes, int n_in,
                              void* d_out, int out_size, void* d_ws, size_t ws_size,
                              hipStream_t stream) {
    const float* x     = (const float*)d_in[0];
    // d_in[1] edge_index, d_in[2] edge_weight: unused (ChebConv K=1 -> identity only)
    const float* w1a   = (const float*)d_in[3];
    const float* b1a   = (const float*)d_in[4];
    const float* w1b   = (const float*)d_in[5];
    const float* b1b   = (const float*)d_in[6];
    const float* w1c   = (const float*)d_in[7];
    const float* b1c   = (const float*)d_in[8];
    const float* chw   = (const float*)d_in[9];
    const float* chb   = (const float*)d_in[10];
    const float* w2a   = (const float*)d_in[11];
    const float* b2a   = (const float*)d_in[12];
    const float* w2b   = (const float*)d_in[13];
    const float* b2b   = (const float*)d_in[14];
    const float* w2c   = (const float*)d_in[15];
    const float* b2c   = (const float*)d_in[16];
    const float* gamma = (const float*)d_in[17];
    const float* beta  = (const float*)d_in[18];
    const float* fcw   = (const float*)d_in[19];
    const float* fcb   = (const float*)d_in[20];
    float* out = (float*)d_out;

    float* ws = (float*)d_ws;
    float* T1v   = ws;                  // 1472256
    float* T2v   = T1v + 1472256;       // 1469952
    float* WT    = T2v + 1469952;       // 36864
    float* parts = WT + 36864;          // 18*40*2 = 1440
    float* stats = parts + 1536;        // 36 (use 64)
    float* dpart = stats + 64;          // 512

    k_wprep<<<48, 256, 0, stream>>>(w2a, w2b, w2c, WT);
    k_fused1<<<NCHUNK1, 256, 0, stream>>>(
        x, w1a, b1a, w1b, b1b, w1c, b1c, chw, chb, T1v);
    k_conv2<<<dim3(NCHUNK2, NN), 256, 0, stream>>>(
        T1v, WT, b2a, b2b, b2c, T2v, parts);
    k_statsfin<<<NN, 64, 0, stream>>>(parts, stats);
    k_dot<<<DOT_BLOCKS, 256, 0, stream>>>(T2v, stats, gamma, beta, fcw, dpart);
    k_final<<<1, 512, 0, stream>>>(dpart, fcb, out);
}

// Round 4
// 41.861 us; speedup vs baseline: 4.1561x; 1.5759x over previous
//
#include <hip/hip_runtime.h>
#include <math.h>

#define NN 18
#define T_STEPS 1280
#define T1LEN 1278   // T-2 (after conv1)
#define T2LEN 1276   // T-4 (after conv2)
#define NPOS1 (T1LEN * NN)   // 23004
#define XTOT  (T_STEPS * NN) // 23040
#define PC1 32
#define NCHUNK1 ((NPOS1 + PC1 - 1) / PC1)  // 719
#define TC2 64
#define NCHUNK2 ((T2LEN + TC2 - 1) / TC2)  // 20

typedef __attribute__((ext_vector_type(8))) short short8;
typedef __attribute__((ext_vector_type(4))) float f32x4;

__device__ __forceinline__ unsigned short f2bf(float v) {
    unsigned u = __builtin_bit_cast(unsigned, v);
    u = u + 0x7fff + ((u >> 16) & 1);          // RNE
    return (unsigned short)(u >> 16);
}
__device__ __forceinline__ float bf2f(unsigned short h) {
    unsigned u = ((unsigned)h) << 16;
    return __builtin_bit_cast(float, u);
}

// ---------------- K0: split conv2 weights to bf16 hi/lo, layout [kb][col][klocal] ----------------
// col = conv*64+co (conv a->P cols 0..63, b->Q 64..127, c->C 128..191)
// K index = k*64+ci ; kb covers 32 contiguous: k=kb>>1, ci=(kb&1)*32+klocal
__global__ void k_wprep2(const float* __restrict__ wa, const float* __restrict__ wb,
                         const float* __restrict__ wc,
                         unsigned short* __restrict__ WBhi, unsigned short* __restrict__ WBlo) {
    int i = blockIdx.x * 256 + threadIdx.x;
    if (i >= 6 * 192 * 32) return;
    int klocal = i & 31;
    int col = (i >> 5) % 192;
    int kb = i / (192 * 32);
    int conv = col >> 6, co = col & 63;
    int k = kb >> 1, ci = (kb & 1) * 32 + klocal;
    const float* w = (conv == 0) ? wa : (conv == 1 ? wb : wc);
    float v = w[co * 192 + ci * 3 + k];
    unsigned short hi = f2bf(v);
    WBhi[i] = hi;
    WBlo[i] = f2bf(v - bf2f(hi));
}

// ---------------- K1: fused normalize + conv1(GLU) + cheb(64x64)+relu -> bf16 hi/lo ----------------
__global__ __launch_bounds__(256) void k_fused1(const float* __restrict__ x,
        const float* __restrict__ w1a, const float* __restrict__ b1a,
        const float* __restrict__ w1b, const float* __restrict__ b1b,
        const float* __restrict__ w1c, const float* __restrict__ b1c,
        const float* __restrict__ cw, const float* __restrict__ cb,
        unsigned short* __restrict__ T1hi, unsigned short* __restrict__ T1lo) {
    __shared__ float xs[72];
    __shared__ float tile[PC1][65];
    int p0 = blockIdx.x * PC1;
    int np = min(PC1, NPOS1 - p0);
    for (int idx = threadIdx.x; idx < PC1 + 36; idx += 256) {
        int g = p0 + idx;
        float v = (g < XTOT) ? x[g] : 0.f;
        xs[idx] = v / fmaxf(fabsf(v), 1e-12f);
    }
    __syncthreads();
    int c = threadIdx.x & 63;
    int w = threadIdx.x >> 6;
    float wa0 = w1a[c*3], wa1 = w1a[c*3+1], wa2 = w1a[c*3+2];
    float wb0 = w1b[c*3], wb1 = w1b[c*3+1], wb2 = w1b[c*3+2];
    float wc0 = w1c[c*3], wc1 = w1c[c*3+1], wc2 = w1c[c*3+2];
    float ba = b1a[c], bb = b1b[c], bc = b1c[c];
    #pragma unroll
    for (int j = 0; j < 8; ++j) {
        int pl = w * 8 + j;
        float x0 = xs[pl], x1 = xs[pl + 18], x2 = xs[pl + 36];
        float pa = fmaf(wa2, x2, fmaf(wa1, x1, fmaf(wa0, x0, ba)));
        float pb = fmaf(wb2, x2, fmaf(wb1, x1, fmaf(wb0, x0, bb)));
        float pc_ = fmaf(wc2, x2, fmaf(wc1, x1, fmaf(wc0, x0, bc)));
        float q = 1.0f / (1.0f + expf(-pb));
        tile[pl][c] = fmaxf(pa * q + pc_, 0.f);
    }
    __syncthreads();
    float acc[8];
    float bias = cb[c];
    #pragma unroll
    for (int j = 0; j < 8; ++j) acc[j] = bias;
    float wcur = cw[c];
    for (int cc = 0; cc < 64; ++cc) {
        float wnxt = cw[((cc + 1) & 63) * 64 + c];
        #pragma unroll
        for (int j = 0; j < 8; ++j)
            acc[j] = fmaf(tile[w * 8 + j][cc], wcur, acc[j]);
        wcur = wnxt;
    }
    #pragma unroll
    for (int j = 0; j < 8; ++j) {
        int p = w * 8 + j;
        if (p < np) {
            float v = fmaxf(acc[j], 0.0f);
            unsigned short hi = f2bf(v);
            int idx = (p0 + p) * 64 + c;
            T1hi[idx] = hi;
            T1lo[idx] = f2bf(v - bf2f(hi));
        }
    }
}

// ---------------- K2: conv2 via split-bf16 MFMA + GLU + BN partials ----------------
// Per node n: C[t,col] = sum_{kb} A[t,kb*32+..] * B[..]; A[t,K]=T1n[t + (kb>>1)][(kb&1)*32+klocal]
__global__ __launch_bounds__(256) void k_conv2m(
        const unsigned short* __restrict__ T1hi, const unsigned short* __restrict__ T1lo,
        const unsigned short* __restrict__ WBhi, const unsigned short* __restrict__ WBlo,
        const float* __restrict__ b2a, const float* __restrict__ b2b,
        const float* __restrict__ b2c,
        float* __restrict__ T2, float* __restrict__ partials) {
    __shared__ uint4 ldsH[528], ldsL[528];   // 66 rows x 8 uint4 (64 bf16/row), XOR-swizzled
    int t0 = blockIdx.x * TC2;
    int n  = blockIdx.y;
    int tid = threadIdx.x;
    int rows_valid = min(66, T1LEN - t0);
    const uint4* gh = (const uint4*)T1hi;
    const uint4* gl = (const uint4*)T1lo;
    for (int idx = tid; idx < 528; idx += 256) {
        int row = idx >> 3, cb = idx & 7;
        uint4 vh = {0,0,0,0}, vl = {0,0,0,0};
        if (row < rows_valid) {
            int g = ((t0 + row) * NN + n) * 8 + cb;
            vh = gh[g]; vl = gl[g];
        }
        int s = row * 8 + (cb ^ (row & 7));
        ldsH[s] = vh; ldsL[s] = vl;
    }
    int l = tid & 63, w = tid >> 6;
    // B fragments: wave w owns col-tiles {w, w+4, w+8} -> P,Q,C for co = w*16+(l&15)
    short8 bh[3][6], bl[3][6];
    const uint4* wbh = (const uint4*)WBhi;
    const uint4* wbl = (const uint4*)WBlo;
    #pragma unroll
    for (int ct = 0; ct < 3; ++ct) {
        int col = (w + 4 * ct) * 16 + (l & 15);
        #pragma unroll
        for (int kb = 0; kb < 6; ++kb) {
            int gi = (kb * 192 + col) * 4 + (l >> 4);
            bh[ct][kb] = __builtin_bit_cast(short8, wbh[gi]);
            bl[ct][kb] = __builtin_bit_cast(short8, wbl[gi]);
        }
    }
    int co = w * 16 + (l & 15);
    float ba = b2a[co], bb = b2b[co], bc = b2c[co];
    __syncthreads();
    float s_sum = 0.f, s_sq = 0.f;
    for (int mt = 0; mt < 4; ++mt) {
        f32x4 accP = {0,0,0,0}, accQ = {0,0,0,0}, accC = {0,0,0,0};
        #pragma unroll
        for (int kb = 0; kb < 6; ++kb) {
            int row = mt * 16 + (l & 15) + (kb >> 1);
            int cb = (kb & 1) * 4 + (l >> 4);
            int si = row * 8 + (cb ^ (row & 7));
            short8 ah = __builtin_bit_cast(short8, ldsH[si]);
            short8 al = __builtin_bit_cast(short8, ldsL[si]);
            accP = __builtin_amdgcn_mfma_f32_16x16x32_bf16(ah, bh[0][kb], accP, 0, 0, 0);
            accQ = __builtin_amdgcn_mfma_f32_16x16x32_bf16(ah, bh[1][kb], accQ, 0, 0, 0);
            accC = __builtin_amdgcn_mfma_f32_16x16x32_bf16(ah, bh[2][kb], accC, 0, 0, 0);
            accP = __builtin_amdgcn_mfma_f32_16x16x32_bf16(al, bh[0][kb], accP, 0, 0, 0);
            accQ = __builtin_amdgcn_mfma_f32_16x16x32_bf16(al, bh[1][kb], accQ, 0, 0, 0);
            accC = __builtin_amdgcn_mfma_f32_16x16x32_bf16(al, bh[2][kb], accC, 0, 0, 0);
            accP = __builtin_amdgcn_mfma_f32_16x16x32_bf16(ah, bl[0][kb], accP, 0, 0, 0);
            accQ = __builtin_amdgcn_mfma_f32_16x16x32_bf16(ah, bl[1][kb], accQ, 0, 0, 0);
            accC = __builtin_amdgcn_mfma_f32_16x16x32_bf16(ah, bl[2][kb], accC, 0, 0, 0);
        }
        #pragma unroll
        for (int r = 0; r < 4; ++r) {
            int t = t0 + mt * 16 + (l >> 4) * 4 + r;
            if (t < T2LEN) {
                float P = accP[r] + ba, Q = accQ[r] + bb, Cc = accC[r] + bc;
                float q = 1.f / (1.f + expf(-Q));
                float h = fmaxf(fmaf(P, q, Cc), 0.f);
                T2[(t * NN + n) * 64 + co] = h;
                s_sum += h;
                s_sq = fmaf(h, h, s_sq);
            }
        }
    }
    __shared__ float rs[256], rq[256];
    rs[tid] = s_sum; rq[tid] = s_sq;
    __syncthreads();
    for (int off = 128; off > 0; off >>= 1) {
        if (tid < off) { rs[tid] += rs[tid + off]; rq[tid] += rq[tid + off]; }
        __syncthreads();
    }
    if (tid == 0) {
        partials[(n * NCHUNK2 + blockIdx.x) * 2]     = rs[0];
        partials[(n * NCHUNK2 + blockIdx.x) * 2 + 1] = rq[0];
    }
}

// ---------------- K3: finalize BN stats per node ----------------
__global__ __launch_bounds__(64) void k_statsfin(const float* __restrict__ partials,
                                                 float* __restrict__ stats) {
    int n = blockIdx.x;
    int l = threadIdx.x;
    float s = (l < NCHUNK2) ? partials[(n * NCHUNK2 + l) * 2]     : 0.f;
    float q = (l < NCHUNK2) ? partials[(n * NCHUNK2 + l) * 2 + 1] : 0.f;
    #pragma unroll
    for (int off = 32; off > 0; off >>= 1) {
        s += __shfl_down(s, off);
        q += __shfl_down(q, off);
    }
    if (l == 0) {
        float cnt = (float)(T2LEN * 64);
        float mean = s / cnt;
        float var = q / cnt - mean * mean;
        stats[n * 2]     = mean;
        stats[n * 2 + 1] = rsqrtf(var + 1e-5f);
    }
}

// ---------------- K4: BN apply + relu + dot with fc_w (float4) ----------------
#define DOT_BLOCKS 512
__global__ __launch_bounds__(256) void k_dot(const float* __restrict__ T2,
        const float* __restrict__ stats,
        const float* __restrict__ gamma, const float* __restrict__ beta,
        const float* __restrict__ fcw, float* __restrict__ dpart) {
    float acc = 0.f;
    const int total4 = T2LEN * NN * 64 / 4;
    const float4* T24 = (const float4*)T2;
    const float4* fw4 = (const float4*)fcw;
    for (int i = blockIdx.x * 256 + threadIdx.x; i < total4; i += DOT_BLOCKS * 256) {
        float4 t = T24[i];
        float4 f = fw4[i];
        int n = (i >> 4) % NN;
        float mu = stats[n * 2], is = stats[n * 2 + 1];
        float g = gamma[n], bt = beta[n];
        float v0 = fmaxf((t.x - mu) * is * g + bt, 0.f);
        float v1 = fmaxf((t.y - mu) * is * g + bt, 0.f);
        float v2 = fmaxf((t.z - mu) * is * g + bt, 0.f);
        float v3 = fmaxf((t.w - mu) * is * g + bt, 0.f);
        acc = fmaf(v0, f.x, acc);
        acc = fmaf(v1, f.y, acc);
        acc = fmaf(v2, f.z, acc);
        acc = fmaf(v3, f.w, acc);
    }
    __shared__ float r[256];
    r[threadIdx.x] = acc;
    __syncthreads();
    for (int off = 128; off > 0; off >>= 1) {
        if (threadIdx.x < off) r[threadIdx.x] += r[threadIdx.x + off];
        __syncthreads();
    }
    if (threadIdx.x == 0) dpart[blockIdx.x] = r[0];
}

// ---------------- K5: final reduce + fc_b ----------------
__global__ __launch_bounds__(512) void k_final(const float* __restrict__ dpart,
                                               const float* __restrict__ fcb,
                                               float* __restrict__ out) {
    __shared__ float r[512];
    r[threadIdx.x] = dpart[threadIdx.x];
    __syncthreads();
    for (int off = 256; off > 0; off >>= 1) {
        if (threadIdx.x < off) r[threadIdx.x] += r[threadIdx.x + off];
        __syncthreads();
    }
    if (threadIdx.x == 0) out[0] = r[0] + fcb[0];
}

extern "C" void kernel_launch(void* const* d_in, const int* in_sizes, int n_in,
                              void* d_out, int out_size, void* d_ws, size_t ws_size,
                              hipStream_t stream) {
    const float* x     = (const float*)d_in[0];
    // d_in[1] edge_index, d_in[2] edge_weight: unused (ChebConv K=1 -> identity only)
    const float* w1a   = (const float*)d_in[3];
    const float* b1a   = (const float*)d_in[4];
    const float* w1b   = (const float*)d_in[5];
    const float* b1b   = (const float*)d_in[6];
    const float* w1c   = (const float*)d_in[7];
    const float* b1c   = (const float*)d_in[8];
    const float* chw   = (const float*)d_in[9];
    const float* chb   = (const float*)d_in[10];
    const float* w2a   = (const float*)d_in[11];
    const float* b2a   = (const float*)d_in[12];
    const float* w2b   = (const float*)d_in[13];
    const float* b2b   = (const float*)d_in[14];
    const float* w2c   = (const float*)d_in[15];
    const float* b2c   = (const float*)d_in[16];
    const float* gamma = (const float*)d_in[17];
    const float* beta  = (const float*)d_in[18];
    const float* fcw   = (const float*)d_in[19];
    const float* fcb   = (const float*)d_in[20];
    float* out = (float*)d_out;

    char* base = (char*)d_ws;
    float*          T2v   = (float*)(base);                    // 1469952 f = 5879808 B
    unsigned short* T1hi  = (unsigned short*)(base + 5879808); // 1472256 us = 2944512 B
    unsigned short* T1lo  = (unsigned short*)(base + 8824320); // 2944512 B
    unsigned short* WBhi  = (unsigned short*)(base + 11768832);// 36864 us = 73728 B
    unsigned short* WBlo  = (unsigned short*)(base + 11842560);// 73728 B
    float*          parts = (float*)(base + 11916288);         // 720 f
    float*          stats = (float*)(base + 11920384);         // 36 f
    float*          dpart = (float*)(base + 11921408);         // 512 f

    k_wprep2<<<144, 256, 0, stream>>>(w2a, w2b, w2c, WBhi, WBlo);
    k_fused1<<<NCHUNK1, 256, 0, stream>>>(
        x, w1a, b1a, w1b, b1b, w1c, b1c, chw, chb, T1hi, T1lo);
    k_conv2m<<<dim3(NCHUNK2, NN), 256, 0, stream>>>(
        T1hi, T1lo, WBhi, WBlo, b2a, b2b, b2c, T2v, parts);
    k_statsfin<<<NN, 64, 0, stream>>>(parts, stats);
    k_dot<<<DOT_BLOCKS, 256, 0, stream>>>(T2v, stats, gamma, beta, fcw, dpart);
    k_final<<<1, 512, 0, stream>>>(dpart, fcb, out);
}